// Round 1
// baseline (245.600 us; speedup 1.0000x reference)
//
#include <hip/hip_runtime.h>
#include <hip/hip_bf16.h>
#include <math.h>

// Problem constants
#define BB    4
#define NNODE 2048
#define DST   64
#define NETW  256
#define INPT  448   // NET + 3*DEST

typedef float f32x4 __attribute__((ext_vector_type(4)));
typedef short s16x8 __attribute__((ext_vector_type(8)));

#define MFMA(a, b, c) __builtin_amdgcn_mfma_f32_16x16x32_bf16((a), (b), (c), 0, 0, 0)

// Persistent device-side workspace (rewritten fully every launch)
__device__ __align__(16) unsigned short g_WcatT[128 * 128];        // bf16 [j][f], j<64: Wf col j, j>=64: Wb col j-64
__device__ __align__(16) unsigned short g_WembT[128 * 256];        // bf16 [c][k]
__device__ __align__(16) unsigned short g_Ut[BB * 128 * NNODE];    // bf16 [b][j][n]  (U transposed)
__device__ __align__(16) float          g_G2[BB * NNODE * 128];    // fp32 dyn*gate

// ---- fp32 -> bf16 (RNE) helpers ----
__device__ __forceinline__ unsigned bf16pk(float a, float b) {
    unsigned ua = __builtin_bit_cast(unsigned, a);
    unsigned ub = __builtin_bit_cast(unsigned, b);
    ua += 0x7fffu + ((ua >> 16) & 1u);
    ub += 0x7fffu + ((ub >> 16) & 1u);
    return (ua >> 16) | (ub & 0xffff0000u);
}
__device__ __forceinline__ unsigned short bf16b(float a) {
    unsigned ua = __builtin_bit_cast(unsigned, a);
    ua += 0x7fffu + ((ua >> 16) & 1u);
    return (unsigned short)(ua >> 16);
}
__device__ __forceinline__ s16x8 pack8(float4 x, float4 y) {
    union { unsigned u[4]; s16x8 s; } r;
    r.u[0] = bf16pk(x.x, x.y);
    r.u[1] = bf16pk(x.z, x.w);
    r.u[2] = bf16pk(y.x, y.y);
    r.u[3] = bf16pk(y.z, y.w);
    return r.s;
}

// ---- k0: weight transpose + bf16 convert (tiny) ----
__global__ void k_weights(const float* __restrict__ Wf, const float* __restrict__ Wb,
                          const float* __restrict__ We) {
    int t = blockIdx.x * blockDim.x + threadIdx.x;
    int stride = gridDim.x * blockDim.x;
    for (int i = t; i < 128 * 128; i += stride) {
        int j = i >> 7, f = i & 127;
        float v = (j < 64) ? Wf[f * 64 + j] : Wb[f * 64 + (j - 64)];
        g_WcatT[i] = bf16b(v);
    }
    for (int i = t; i < 128 * 256; i += stride) {
        int c = i >> 8, k = i & 255;
        g_WembT[i] = bf16b(We[k * 128 + c]);
    }
}

// ---- k1: bid<128 -> Ut = Wcat^T @ struct^T ; bid>=128 -> G2 = dyn*sigmoid(stat@W_emb+b_emb) ----
__global__ __launch_bounds__(256) void k_prep(const float* __restrict__ nfeat,
                                              const float* __restrict__ bemb) {
    int w  = threadIdx.x >> 6;
    int l  = threadIdx.x & 63;
    int lr = l & 15, lc = l >> 4;
    int bid = blockIdx.x;

    if (bid < 128) {
        // Ut part: per batch, D[j 0..127][n 0..2047] = sum_f WcatT[j][f]*struct[n][f]
        int b = bid >> 5;
        int mbase = (bid & 31) * 64;          // 64 n-columns per wg
        f32x4 acc[2][4] = {};
        #pragma unroll
        for (int kg = 0; kg < 4; ++kg) {      // K=128 in 4 steps of 32
            s16x8 a0 = *(const s16x8*)&g_WcatT[((2 * w + 0) * 16 + lr) * 128 + kg * 32 + lc * 8];
            s16x8 a1 = *(const s16x8*)&g_WcatT[((2 * w + 1) * 16 + lr) * 128 + kg * 32 + lc * 8];
            #pragma unroll
            for (int nf = 0; nf < 4; ++nf) {
                int np = mbase + nf * 16 + lr;
                const float* p = nfeat + (size_t)(b * NNODE + np) * INPT + DST + kg * 32 + lc * 8;
                float4 x0 = *(const float4*)p;
                float4 x1 = *(const float4*)(p + 4);
                s16x8 bfr = pack8(x0, x1);
                acc[0][nf] = MFMA(a0, bfr, acc[0][nf]);
                acc[1][nf] = MFMA(a1, bfr, acc[1][nf]);
            }
        }
        #pragma unroll
        for (int ja = 0; ja < 2; ++ja)
            #pragma unroll
            for (int nf = 0; nf < 4; ++nf) {
                int np = mbase + nf * 16 + lr;
                #pragma unroll
                for (int r = 0; r < 4; ++r) {
                    int j = (2 * w + ja) * 16 + lc * 4 + r;
                    g_Ut[(size_t)(b * 128 + j) * NNODE + np] = bf16b(acc[ja][nf][r]);
                }
            }
    } else {
        // G2 part: D[m][c 0..127] = stat[m] @ W_emb ; G2 = dyn[c&63]*sigmoid(D + b_emb)
        int bid2 = bid - 128;
        int b = bid2 >> 5;
        int mbase = (bid2 & 31) * 64;
        int ma = mbase + w * 16 + lr;         // A row
        f32x4 acc[8] = {};
        #pragma unroll
        for (int kg = 0; kg < 8; ++kg) {      // K=256 in 8 steps of 32
            const float* p = nfeat + (size_t)(b * NNODE + ma) * INPT + 3 * DST + kg * 32 + lc * 8;
            float4 x0 = *(const float4*)p;
            float4 x1 = *(const float4*)(p + 4);
            s16x8 a = pack8(x0, x1);
            #pragma unroll
            for (int nf = 0; nf < 8; ++nf) {
                s16x8 bfr = *(const s16x8*)&g_WembT[(nf * 16 + lr) * 256 + kg * 32 + lc * 8];
                acc[nf] = MFMA(a, bfr, acc[nf]);
            }
        }
        #pragma unroll
        for (int nf = 0; nf < 8; ++nf) {
            int c = nf * 16 + lr;
            float be = bemb[c];
            #pragma unroll
            for (int r = 0; r < 4; ++r) {
                int mm = mbase + w * 16 + lc * 4 + r;
                float v = acc[nf][r] + be;
                float g = 1.0f / (1.0f + expf(-v));
                g_G2[(size_t)(b * NNODE + mm) * 128 + c] =
                    g * nfeat[(size_t)(b * NNODE + mm) * INPT + (c & 63)];
            }
        }
    }
}

// ---- k2: main GEMM  h = adj @ U  (M=2048,K=2048,N=64 per (b,dir)), fused epilogue ----
__global__ __launch_bounds__(256) void k_main(const float* __restrict__ adjf,
                                              const float* __restrict__ adjb,
                                              const float* __restrict__ biasf,
                                              const float* __restrict__ biasb,
                                              float* __restrict__ out) {
    int bid  = blockIdx.x;
    int tile = bid & 31;
    int dir  = (bid >> 5) & 1;
    int b    = bid >> 6;
    int w  = threadIdx.x >> 6;
    int l  = threadIdx.x & 63;
    int lr = l & 15, lc = l >> 4;

    const float* adj  = dir ? adjb : adjf;
    const float* bias = dir ? biasb : biasf;
    int m0 = tile * 64 + w * 16;                       // this wave's 16 rows
    const float* arow = adj + (size_t)(b * NNODE + m0 + lr) * NNODE + lc * 8;
    const unsigned short* ut = g_Ut + (size_t)(b * 128 + dir * 64) * NNODE;

    f32x4 acc[4] = {};
    for (int ko = 0; ko < 4; ++ko) {
        #pragma unroll 4
        for (int ki = 0; ki < 16; ++ki) {
            int kg = ko * 16 + ki;
            const float4* pa = (const float4*)(arow + (size_t)kg * 32);
            float4 x0 = pa[0];
            float4 x1 = pa[1];
            s16x8 a = pack8(x0, x1);
            #pragma unroll
            for (int nf = 0; nf < 4; ++nf) {
                s16x8 bfr = *(const s16x8*)&ut[(nf * 16 + lr) * NNODE + kg * 32 + lc * 8];
                acc[nf] = MFMA(a, bfr, acc[nf]);
            }
        }
        __syncthreads();   // keep the 4 waves' B-streams aligned for L1 reuse
    }

    #pragma unroll
    for (int nf = 0; nf < 4; ++nf) {
        int col = nf * 16 + lr;
        float bv = bias[col];
        #pragma unroll
        for (int r = 0; r < 4; ++r) {
            int m = tile * 64 + w * 16 + lc * 4 + r;
            size_t o = (size_t)(b * NNODE + m) * 128 + dir * 64 + col;
            out[o] = (acc[nf][r] + bv) * g_G2[o];
        }
    }
}

extern "C" void kernel_launch(void* const* d_in, const int* in_sizes, int n_in,
                              void* d_out, int out_size, void* d_ws, size_t ws_size,
                              hipStream_t stream) {
    (void)in_sizes; (void)n_in; (void)d_ws; (void)ws_size; (void)out_size;
    const float* nfeat = (const float*)d_in[0];
    const float* adjf  = (const float*)d_in[1];
    const float* adjb  = (const float*)d_in[2];
    const float* Wf    = (const float*)d_in[3];
    const float* bf    = (const float*)d_in[4];
    const float* Wb    = (const float*)d_in[5];
    const float* bb    = (const float*)d_in[6];
    const float* We    = (const float*)d_in[7];
    const float* bemb  = (const float*)d_in[8];
    float* out = (float*)d_out;

    hipLaunchKernelGGL(k_weights, dim3(64),  dim3(256), 0, stream, Wf, Wb, We);
    hipLaunchKernelGGL(k_prep,    dim3(256), dim3(256), 0, stream, nfeat, bemb);
    hipLaunchKernelGGL(k_main,    dim3(256), dim3(256), 0, stream, adjf, adjb, bf, bb, out);
}

// Round 2
// 224.076 us; speedup vs baseline: 1.0961x; 1.0961x over previous
//
#include <hip/hip_runtime.h>
#include <hip/hip_bf16.h>
#include <math.h>

// Problem constants
#define BB    4
#define NNODE 2048
#define DST   64
#define NETW  256
#define INPT  448   // NET + 3*DEST

typedef float f32x4 __attribute__((ext_vector_type(4)));
typedef short s16x8 __attribute__((ext_vector_type(8)));

#define MFMA(a, b, c) __builtin_amdgcn_mfma_f32_16x16x32_bf16((a), (b), (c), 0, 0, 0)

// Persistent device-side workspace (rewritten fully every launch)
__device__ __align__(16) unsigned short g_WcatT[128 * 128];        // bf16 [j][f]
__device__ __align__(16) unsigned short g_WembT[128 * 256];        // bf16 [c][k]
__device__ __align__(16) unsigned short g_Ut[BB * 128 * NNODE];    // bf16 [b][j][n]
__device__ __align__(16) float          g_G2[BB * NNODE * 128];    // fp32 dyn*gate

// ---- fp32 -> bf16 (RNE) helpers ----
__device__ __forceinline__ unsigned bf16pk(float a, float b) {
    unsigned ua = __builtin_bit_cast(unsigned, a);
    unsigned ub = __builtin_bit_cast(unsigned, b);
    ua += 0x7fffu + ((ua >> 16) & 1u);
    ub += 0x7fffu + ((ub >> 16) & 1u);
    return (ua >> 16) | (ub & 0xffff0000u);
}
__device__ __forceinline__ unsigned short bf16b(float a) {
    unsigned ua = __builtin_bit_cast(unsigned, a);
    ua += 0x7fffu + ((ua >> 16) & 1u);
    return (unsigned short)(ua >> 16);
}
__device__ __forceinline__ s16x8 pack8(float4 x, float4 y) {
    union { unsigned u[4]; s16x8 s; } r;
    r.u[0] = bf16pk(x.x, x.y);
    r.u[1] = bf16pk(x.z, x.w);
    r.u[2] = bf16pk(y.x, y.y);
    r.u[3] = bf16pk(y.z, y.w);
    return r.s;
}

// ---- k0: weight transpose + bf16 convert (tiny) ----
__global__ void k_weights(const float* __restrict__ Wf, const float* __restrict__ Wb,
                          const float* __restrict__ We) {
    int t = blockIdx.x * blockDim.x + threadIdx.x;
    int stride = gridDim.x * blockDim.x;
    for (int i = t; i < 128 * 128; i += stride) {
        int j = i >> 7, f = i & 127;
        float v = (j < 64) ? Wf[f * 64 + j] : Wb[f * 64 + (j - 64)];
        g_WcatT[i] = bf16b(v);
    }
    for (int i = t; i < 128 * 256; i += stride) {
        int c = i >> 8, k = i & 255;
        g_WembT[i] = bf16b(We[k * 128 + c]);
    }
}

// ---- k1: bid<512 -> Ut = Wcat^T @ struct^T ; bid>=512 -> G2 = dyn*sigmoid(stat@W_emb+b_emb) ----
__global__ __launch_bounds__(256) void k_prep(const float* __restrict__ nfeat,
                                              const float* __restrict__ bemb) {
    int w  = threadIdx.x >> 6;
    int l  = threadIdx.x & 63;
    int lr = l & 15, lc = l >> 4;
    int bid = blockIdx.x;

    if (bid < 512) {
        // Ut: per batch, D[j 0..127][n16] = sum_f WcatT[j][f]*struct[n][f]
        int b = bid >> 7;
        int nbase = (bid & 127) * 16;         // 16 n-columns per wg
        f32x4 acc[2] = {};
        #pragma unroll
        for (int kg = 0; kg < 4; ++kg) {      // K=128 in 4 steps of 32
            s16x8 a0 = *(const s16x8*)&g_WcatT[((2 * w + 0) * 16 + lr) * 128 + kg * 32 + lc * 8];
            s16x8 a1 = *(const s16x8*)&g_WcatT[((2 * w + 1) * 16 + lr) * 128 + kg * 32 + lc * 8];
            const float* p = nfeat + (size_t)(b * NNODE + nbase + lr) * INPT + DST + kg * 32 + lc * 8;
            float4 x0 = *(const float4*)p;
            float4 x1 = *(const float4*)(p + 4);
            s16x8 bfr = pack8(x0, x1);
            acc[0] = MFMA(a0, bfr, acc[0]);
            acc[1] = MFMA(a1, bfr, acc[1]);
        }
        #pragma unroll
        for (int ja = 0; ja < 2; ++ja)
            #pragma unroll
            for (int r = 0; r < 4; ++r) {
                int j = (2 * w + ja) * 16 + lc * 4 + r;
                g_Ut[(size_t)(b * 128 + j) * NNODE + nbase + lr] = bf16b(acc[ja][r]);
            }
    } else {
        // G2: D[m16][c 0..127] = stat @ W_emb ; G2 = dyn[c&63]*sigmoid(D + b_emb)
        int bid2 = bid - 512;
        int b = bid2 >> 7;
        int mbase = (bid2 & 127) * 16;
        f32x4 acc[2] = {};
        #pragma unroll
        for (int kg = 0; kg < 8; ++kg) {      // K=256 in 8 steps of 32
            const float* p = nfeat + (size_t)(b * NNODE + mbase + lr) * INPT + 3 * DST + kg * 32 + lc * 8;
            float4 x0 = *(const float4*)p;
            float4 x1 = *(const float4*)(p + 4);
            s16x8 a = pack8(x0, x1);
            #pragma unroll
            for (int ca = 0; ca < 2; ++ca) {
                int nf = 2 * w + ca;
                s16x8 bfr = *(const s16x8*)&g_WembT[(nf * 16 + lr) * 256 + kg * 32 + lc * 8];
                acc[ca] = MFMA(a, bfr, acc[ca]);
            }
        }
        #pragma unroll
        for (int ca = 0; ca < 2; ++ca) {
            int c = (2 * w + ca) * 16 + lr;
            float be = bemb[c];
            #pragma unroll
            for (int r = 0; r < 4; ++r) {
                int mm = mbase + lc * 4 + r;
                float v = acc[ca][r] + be;
                float g = 1.0f / (1.0f + expf(-v));
                g_G2[(size_t)(b * NNODE + mm) * 128 + c] =
                    g * nfeat[(size_t)(b * NNODE + mm) * INPT + (c & 63)];
            }
        }
    }
}

// ---- k2: main GEMM  h = adj @ U  (M=2048,K=2048,N=64 per (b,dir)), split-K x8, fused epilogue ----
#define KW 8
__global__ __launch_bounds__(512) void k_main(const float* __restrict__ adjf,
                                              const float* __restrict__ adjb,
                                              const float* __restrict__ biasf,
                                              const float* __restrict__ biasb,
                                              float* __restrict__ out) {
    int bid  = blockIdx.x;                 // 4*2*128 = 1024
    int tile = bid & 127;                  // 16-row m-tile
    int dir  = (bid >> 7) & 1;
    int b    = bid >> 8;
    int w  = threadIdx.x >> 6;             // 0..7 (K-chunk)
    int l  = threadIdx.x & 63;
    int lr = l & 15, lc = l >> 4;

    const float* adj  = dir ? adjb : adjf;
    const float* bias = dir ? biasb : biasf;
    int m0 = tile * 16;
    int k0 = w * 256;
    const float* arow = adj + (size_t)(b * NNODE + m0 + lr) * NNODE + k0 + lc * 8;
    const unsigned short* ut = g_Ut + (size_t)(b * 128 + dir * 64) * NNODE + k0;

    f32x4 acc[4] = {};
    #pragma unroll
    for (int ki = 0; ki < 8; ++ki) {       // 256 K per wave, 32 per step
        const float4* pa = (const float4*)(arow + ki * 32);
        float4 x0 = pa[0];
        float4 x1 = pa[1];
        s16x8 a = pack8(x0, x1);
        #pragma unroll
        for (int nf = 0; nf < 4; ++nf) {
            s16x8 bfr = *(const s16x8*)&ut[(nf * 16 + lr) * NNODE + ki * 32 + lc * 8];
            acc[nf] = MFMA(a, bfr, acc[nf]);
        }
    }

    // cross-wave K reduction through LDS: [wave][nf*4+r][lane] (lane-contiguous, conflict-free)
    __shared__ float lds[KW][16][64];
    #pragma unroll
    for (int nf = 0; nf < 4; ++nf)
        #pragma unroll
        for (int r = 0; r < 4; ++r)
            lds[w][nf * 4 + r][l] = acc[nf][r];
    __syncthreads();

    if (w < 4) {                           // wave w owns column group nf = w
        #pragma unroll
        for (int r = 0; r < 4; ++r) {
            float s = 0.f;
            #pragma unroll
            for (int wp = 0; wp < KW; ++wp)
                s += lds[wp][w * 4 + r][l];
            int col = w * 16 + lr;
            int m   = m0 + lc * 4 + r;
            size_t o = (size_t)(b * NNODE + m) * 128 + dir * 64 + col;
            out[o] = (s + bias[col]) * g_G2[o];
        }
    }
}

extern "C" void kernel_launch(void* const* d_in, const int* in_sizes, int n_in,
                              void* d_out, int out_size, void* d_ws, size_t ws_size,
                              hipStream_t stream) {
    (void)in_sizes; (void)n_in; (void)d_ws; (void)ws_size; (void)out_size;
    const float* nfeat = (const float*)d_in[0];
    const float* adjf  = (const float*)d_in[1];
    const float* adjb  = (const float*)d_in[2];
    const float* Wf    = (const float*)d_in[3];
    const float* bf    = (const float*)d_in[4];
    const float* Wb    = (const float*)d_in[5];
    const float* bb    = (const float*)d_in[6];
    const float* We    = (const float*)d_in[7];
    const float* bemb  = (const float*)d_in[8];
    float* out = (float*)d_out;

    hipLaunchKernelGGL(k_weights, dim3(64),   dim3(256), 0, stream, Wf, Wb, We);
    hipLaunchKernelGGL(k_prep,    dim3(1024), dim3(256), 0, stream, nfeat, bemb);
    hipLaunchKernelGGL(k_main,    dim3(1024), dim3(512), 0, stream, adjf, adjb, bf, bb, out);
}

// Round 3
// 187.297 us; speedup vs baseline: 1.3113x; 1.1964x over previous
//
#include <hip/hip_runtime.h>
#include <hip/hip_bf16.h>
#include <math.h>

#define BB   4
#define NN   2048
#define INPT 448

typedef float f32x4 __attribute__((ext_vector_type(4)));
typedef short s16x8 __attribute__((ext_vector_type(8)));
typedef unsigned int u32;

#define MFMA(a,b,c) __builtin_amdgcn_mfma_f32_16x16x32_bf16((a),(b),(c),0,0,0)

// Fragment-layout persistent buffers (fully rewritten every launch)
__device__ __align__(16) unsigned short g_WcatF[4*8*64*8];       // (kg,jf,l) A-frag words
__device__ __align__(16) unsigned short g_WembF[8*8*64*8];       // (kg,cf,l) B-frag words
__device__ __align__(16) unsigned short g_UtF[BB*2*64*4*64*8];   // (b,dir,kk,nf,l) B-frag words, 2MB
__device__ __align__(16) float          g_G2[BB*NN*128];         // fp32 dyn*gate

// ---- fp32 -> bf16 (RNE) helpers ----
__device__ __forceinline__ u32 bf16pk(float a, float b) {
    u32 ua = __builtin_bit_cast(u32, a);
    u32 ub = __builtin_bit_cast(u32, b);
    ua += 0x7fffu + ((ua >> 16) & 1u);
    ub += 0x7fffu + ((ub >> 16) & 1u);
    return (ua >> 16) | (ub & 0xffff0000u);
}
__device__ __forceinline__ unsigned short bf16b(float a) {
    u32 ua = __builtin_bit_cast(u32, a);
    ua += 0x7fffu + ((ua >> 16) & 1u);
    return (unsigned short)(ua >> 16);
}

// ---- k0: pack weights into MFMA fragment layout ----
__global__ void k_weights(const float* __restrict__ Wf, const float* __restrict__ Wb,
                          const float* __restrict__ We) {
    int t = blockIdx.x * 256 + threadIdx.x;
    if (t < 2048) {                          // WcatF word t = (kg*8 + jf)*64 + l
        int l = t & 63, jf = (t >> 6) & 7, kg = t >> 9;
        int j  = jf * 16 + (l & 15);
        int f0 = kg * 32 + (l >> 4) * 8;
        union { u32 u[4]; s16x8 s; } r;
        #pragma unroll
        for (int e = 0; e < 8; e += 2) {
            float v0 = (j < 64) ? Wf[(f0 + e    ) * 64 + j] : Wb[(f0 + e    ) * 64 + (j - 64)];
            float v1 = (j < 64) ? Wf[(f0 + e + 1) * 64 + j] : Wb[(f0 + e + 1) * 64 + (j - 64)];
            r.u[e >> 1] = bf16pk(v0, v1);
        }
        *(s16x8*)&g_WcatF[t * 8] = r.s;
    } else if (t < 2048 + 4096) {            // WembF word idx = (kg*8 + cf)*64 + l
        int idx = t - 2048;
        int l = idx & 63, cf = (idx >> 6) & 7, kg = idx >> 9;
        int c  = cf * 16 + (l & 15);
        int k0 = kg * 32 + (l >> 4) * 8;
        union { u32 u[4]; s16x8 s; } r;
        #pragma unroll
        for (int e = 0; e < 8; e += 2)
            r.u[e >> 1] = bf16pk(We[(k0 + e) * 128 + c], We[(k0 + e + 1) * 128 + c]);
        *(s16x8*)&g_WembF[idx * 8] = r.s;
    }
}

// ---- k1: bid<256 -> UtF (frag layout); bid>=256 -> G2 ----
__global__ __launch_bounds__(256) void k_prep(const float* __restrict__ nfeat,
                                              const float* __restrict__ bemb) {
    __shared__ __align__(16) char sm[24576];
    int tid = threadIdx.x;
    int w = tid >> 6, l = tid & 63, lr = l & 15, lc = l >> 4;
    int bid = blockIdx.x;

    if (bid < 256) {
        int b = bid >> 6, nb = bid & 63;
        unsigned short* ss = (unsigned short*)sm;            // [32 n][128 f] bf16, XOR-swz
        unsigned short* ob = (unsigned short*)(sm + 8192);   // [128 j][32 n] bf16
        const float* base = nfeat + (size_t)(b * NN + nb * 32) * INPT;
        #pragma unroll
        for (int i = 0; i < 4; ++i) {                        // coalesced struct stage
            int node = w * 8 + i * 2 + (l >> 5);
            int c4 = (l & 31) * 4;
            float4 v = *(const float4*)(base + (size_t)node * INPT + 64 + c4);
            int off = node * 256 + c4 * 2; off ^= (node & 7) << 4;
            uint2 pk; pk.x = bf16pk(v.x, v.y); pk.y = bf16pk(v.z, v.w);
            *(uint2*)((char*)ss + off) = pk;
        }
        __syncthreads();
        f32x4 acc[2][2] = {};
        #pragma unroll
        for (int kg = 0; kg < 4; ++kg) {
            s16x8 a0 = *(const s16x8*)&g_WcatF[((kg * 8 + w * 2 + 0) * 64 + l) * 8];
            s16x8 a1 = *(const s16x8*)&g_WcatF[((kg * 8 + w * 2 + 1) * 64 + l) * 8];
            #pragma unroll
            for (int na = 0; na < 2; ++na) {
                int off = (na * 16 + lr) * 256 + kg * 64 + lc * 16; off ^= (lr & 7) << 4;
                s16x8 bf = *(const s16x8*)((char*)ss + off);
                acc[0][na] = MFMA(a0, bf, acc[0][na]);
                acc[1][na] = MFMA(a1, bf, acc[1][na]);
            }
        }
        #pragma unroll
        for (int ja = 0; ja < 2; ++ja)
            #pragma unroll
            for (int na = 0; na < 2; ++na)
                #pragma unroll
                for (int r = 0; r < 4; ++r) {
                    int j = w * 32 + ja * 16 + lc * 4 + r;
                    int n = na * 16 + lr;
                    ob[j * 32 + n] = bf16b(acc[ja][na][r]);
                }
        __syncthreads();
        #pragma unroll
        for (int q = 0; q < 2; ++q) {                        // frag-order write, coalesced
            int idx = q * 256 + tid;
            int dirx = idx >> 8, nf = (idx >> 6) & 3, ll = idx & 63;
            int j = dirx * 64 + nf * 16 + (ll & 15);
            int n0 = (ll >> 4) * 8;
            s16x8 v = *(const s16x8*)&ob[j * 32 + n0];
            *(s16x8*)&g_UtF[((((size_t)(b * 2 + dirx) * 64 + nb) * 4 + nf) * 64 + ll) * 8] = v;
        }
    } else {
        int bid2 = bid - 256;
        int b = bid2 >> 6, mb = bid2 & 63;
        unsigned short* ss = (unsigned short*)sm;            // [32 m][256 k] bf16, XOR-swz
        float* dyls = (float*)(sm + 16384);                  // [32 m][64] f32
        const float* base = nfeat + (size_t)(b * NN + mb * 32) * INPT;
        #pragma unroll
        for (int i = 0; i < 8; ++i) {                        // coalesced stat stage
            int row = w * 8 + i;
            float4 v = *(const float4*)(base + (size_t)row * INPT + 192 + l * 4);
            int off = row * 512 + l * 8; off ^= (row & 7) << 4;
            uint2 pk; pk.x = bf16pk(v.x, v.y); pk.y = bf16pk(v.z, v.w);
            *(uint2*)((char*)ss + off) = pk;
        }
        #pragma unroll
        for (int i = 0; i < 2; ++i) {                        // dyn stage (fp32)
            int row = w * 8 + i * 4 + lc;
            float4 v = *(const float4*)(base + (size_t)row * INPT + lr * 4);
            *(float4*)&dyls[row * 64 + lr * 4] = v;
        }
        __syncthreads();
        f32x4 acc[2][2] = {};
        #pragma unroll
        for (int kg = 0; kg < 8; ++kg) {
            s16x8 a0, a1;
            {
                int off = lr * 512 + kg * 64 + lc * 16; off ^= (lr & 7) << 4;
                a0 = *(const s16x8*)((char*)ss + off);
                a1 = *(const s16x8*)((char*)ss + off + 8192);
            }
            #pragma unroll
            for (int cfi = 0; cfi < 2; ++cfi) {
                s16x8 bf = *(const s16x8*)&g_WembF[((kg * 8 + w * 2 + cfi) * 64 + l) * 8];
                acc[cfi][0] = MFMA(a0, bf, acc[cfi][0]);
                acc[cfi][1] = MFMA(a1, bf, acc[cfi][1]);
            }
        }
        #pragma unroll
        for (int cfi = 0; cfi < 2; ++cfi) {
            int c = (w * 2 + cfi) * 16 + lr;
            float be = bemb[c];
            #pragma unroll
            for (int mf = 0; mf < 2; ++mf)
                #pragma unroll
                for (int r = 0; r < 4; ++r) {
                    int m = mf * 16 + lc * 4 + r;
                    float v = acc[cfi][mf][r] + be;
                    float g = 1.0f / (1.0f + expf(-v));
                    g_G2[(size_t)(b * NN + mb * 32 + m) * 128 + c] = g * dyls[m * 64 + (c & 63)];
                }
        }
    }
}
// NOTE: stat frag rows mf*16+lr: (mf*16+lr)&7 == lr&7, so a1 = a0's offset + 16*512 bytes = +8192. 

// ---- k2: main GEMM h = adj @ U, split-K x8, per-wave-private LDS staging, no main-loop barriers ----
__global__ __launch_bounds__(512, 4) void k_main(const float* __restrict__ adjf,
                                                 const float* __restrict__ adjb,
                                                 const float* __restrict__ biasf,
                                                 const float* __restrict__ biasb,
                                                 float* __restrict__ out) {
    __shared__ __align__(16) char sm[32768];     // per-wave 4KB: 2x 2KB A-chunk dbuf; reused as reduce
    int tid = threadIdx.x;
    int w = tid >> 6, l = tid & 63, lr = l & 15, lc = l >> 4;
    int bid = blockIdx.x;
    int tile = bid & 127, dir = (bid >> 7) & 1, b = bid >> 8;
    const float* adj  = dir ? adjb : adjf;
    const float* bias = dir ? biasb : biasf;
    int m0 = tile * 16;
    const unsigned short* utF = g_UtF + (size_t)(b * 2 + dir) * 131072;
    const float* ag = adj + (size_t)(b * NN + m0) * NN + w * 256;
    char* abase = sm + w * 4096;

    f32x4 acc[4] = {};
    float4 av[4];
    #pragma unroll
    for (int i = 0; i < 4; ++i)                  // prologue: chunk 0, coalesced 256B segments
        av[i] = *(const float4*)(ag + (size_t)(4 * i + lc) * NN + (l & 15) * 4);

    for (int c = 0; c < 4; ++c) {
        float4 avn[4];
        if (c < 3) {
            #pragma unroll
            for (int i = 0; i < 4; ++i)          // prefetch next chunk (in flight across this chunk)
                avn[i] = *(const float4*)(ag + (size_t)(4 * i + lc) * NN + (c + 1) * 64 + (l & 15) * 4);
        }
        char* abuf = abase + (c & 1) * 2048;
        #pragma unroll
        for (int i = 0; i < 4; ++i) {            // convert + swizzled LDS write (wave-private)
            int row = 4 * i + lc;
            int off = row * 128 + (l & 15) * 8; off ^= (row & 7) << 4;
            uint2 pk; pk.x = bf16pk(av[i].x, av[i].y); pk.y = bf16pk(av[i].z, av[i].w);
            *(uint2*)(abuf + off) = pk;
        }
        #pragma unroll
        for (int ii = 0; ii < 2; ++ii) {
            int off = lr * 128 + ii * 64 + lc * 16; off ^= (lr & 7) << 4;
            s16x8 af = *(const s16x8*)(abuf + off);
            int kk = w * 8 + c * 2 + ii;
            #pragma unroll
            for (int nf = 0; nf < 4; ++nf) {     // B: coalesced 1KB frag words, L2-resident
                s16x8 bf = *(const s16x8*)&utF[((kk * 4 + nf) * 64 + l) * 8];
                acc[nf] = MFMA(af, bf, acc[nf]);
            }
        }
        if (c < 3) { av[0] = avn[0]; av[1] = avn[1]; av[2] = avn[2]; av[3] = avn[3]; }
    }

    // cross-wave K reduction (reuse LDS; each wave writes only its own aliased region)
    float* red = (float*)sm;
    #pragma unroll
    for (int nf = 0; nf < 4; ++nf)
        #pragma unroll
        for (int r = 0; r < 4; ++r)
            red[(w * 16 + nf * 4 + r) * 64 + l] = acc[nf][r];
    __syncthreads();
    if (w < 4) {
        #pragma unroll
        for (int r = 0; r < 4; ++r) {
            float s = 0.f;
            #pragma unroll
            for (int wp = 0; wp < 8; ++wp)
                s += red[(wp * 16 + w * 4 + r) * 64 + l];
            int col = w * 16 + lr;
            int m = m0 + lc * 4 + r;
            size_t o = (size_t)(b * NN + m) * 128 + dir * 64 + col;
            out[o] = (s + bias[col]) * g_G2[o];
        }
    }
}

extern "C" void kernel_launch(void* const* d_in, const int* in_sizes, int n_in,
                              void* d_out, int out_size, void* d_ws, size_t ws_size,
                              hipStream_t stream) {
    (void)in_sizes; (void)n_in; (void)d_ws; (void)ws_size; (void)out_size;
    const float* nfeat = (const float*)d_in[0];
    const float* adjf  = (const float*)d_in[1];
    const float* adjb  = (const float*)d_in[2];
    const float* Wf    = (const float*)d_in[3];
    const float* bf    = (const float*)d_in[4];
    const float* Wb    = (const float*)d_in[5];
    const float* bb    = (const float*)d_in[6];
    const float* We    = (const float*)d_in[7];
    const float* bemb  = (const float*)d_in[8];
    float* out = (float*)d_out;

    hipLaunchKernelGGL(k_weights, dim3(24),   dim3(256), 0, stream, Wf, Wb, We);
    hipLaunchKernelGGL(k_prep,    dim3(512),  dim3(256), 0, stream, nfeat, bemb);
    hipLaunchKernelGGL(k_main,    dim3(1024), dim3(512), 0, stream, adjf, adjb, bf, bb, out);
}